// Round 3
// baseline (434.780 us; speedup 1.0000x reference)
//
#include <hip/hip_runtime.h>

#define NN 100000
#define NE 1000000
#define NBLK 98          // ceil(NN / 1024) scan blocks
#define CPB 64           // cols per bagg block (4 lanes each)

// ---------------------------------------------------------------------------
// K0: block 0 fuses the whole linear chain into Mt[128][24]:
//   Mt[k][0..20] = fused GCN->layer1 matrix column k ([Wu@W1_top; Wm@W1_bot])
//   Mt[k][21]    = b1'[k],  Mt[k][22] = W2[k]
// blocks 1..256 zero cnt[NN] + degf[NN] (200,000 ints).
// ---------------------------------------------------------------------------
__global__ __launch_bounds__(128) void fuse_zero_kernel(const float* __restrict__ Wu,
                                                        const float* __restrict__ bu,
                                                        const float* __restrict__ Wm,
                                                        const float* __restrict__ bm,
                                                        const float* __restrict__ W1,
                                                        const float* __restrict__ b1,
                                                        const float* __restrict__ W2,
                                                        float* __restrict__ Mt,
                                                        int* __restrict__ zbuf) {
    if (blockIdx.x != 0) {
        for (int i = (blockIdx.x - 1) * 128 + threadIdx.x; i < 2 * NN; i += 256 * 128)
            zbuf[i] = 0;
        return;
    }
    const int j = threadIdx.x;
    float w1c[128];
#pragma unroll
    for (int k = 0; k < 128; k++) w1c[k] = W1[k * 128 + j];

    float* row = Mt + j * 24;
#pragma unroll
    for (int m = 0; m < 3; m++) {
        float acc = 0.f;
#pragma unroll
        for (int k = 0; k < 64; k++) acc = fmaf(Wu[m * 64 + k], w1c[k], acc);
        row[m] = acc;
    }
#pragma unroll
    for (int m = 0; m < 18; m++) {
        float acc = 0.f;
#pragma unroll
        for (int k = 0; k < 64; k++) acc = fmaf(Wm[m * 64 + k], w1c[64 + k], acc);
        row[3 + m] = acc;
    }
    float bp = b1[j];
#pragma unroll
    for (int k = 0; k < 64; k++) {
        bp = fmaf(bu[k], w1c[k], bp);
        bp = fmaf(bm[k], w1c[64 + k], bp);
    }
    row[21] = bp;
    row[22] = W2[j];
    row[23] = 0.f;
}

// ---------------------------------------------------------------------------
// K1: per-col edge count + weighted degree. Fire-and-forget global atomics
// (~10 ops per address, no contention hotspot).
// ---------------------------------------------------------------------------
__global__ __launch_bounds__(256) void cnt_deg_kernel(const int* __restrict__ ei,
                                                      const float* __restrict__ ew,
                                                      int* __restrict__ cnt,
                                                      float* __restrict__ degf) {
    for (int e = blockIdx.x * 256 + threadIdx.x; e < NE; e += 1024 * 256) {
        const int c = ei[NE + e];
        atomicAdd(&cnt[c], 1);
        atomicAdd(&degf[c], ew[e]);
    }
}

// ---------------------------------------------------------------------------
// K2: per-1024-chunk sums of cnt (coalesced).
// ---------------------------------------------------------------------------
__global__ __launch_bounds__(1024) void bsum_kernel(const int* __restrict__ cnt,
                                                    int* __restrict__ bsum) {
    __shared__ int s[1024];
    const int g = blockIdx.x * 1024 + threadIdx.x;
    s[threadIdx.x] = (g < NN) ? cnt[g] : 0;
    __syncthreads();
    for (int off = 512; off > 0; off >>= 1) {
        if (threadIdx.x < off) s[threadIdx.x] += s[threadIdx.x + off];
        __syncthreads();
    }
    if (threadIdx.x == 0) bsum[blockIdx.x] = s[0];
}

// ---------------------------------------------------------------------------
// K3: exclusive scan of the 98 chunk sums; also H0[NN] = NE.
// ---------------------------------------------------------------------------
__global__ __launch_bounds__(128) void bscan_kernel(const int* __restrict__ bsum,
                                                    int* __restrict__ bbase,
                                                    int* __restrict__ H0) {
    __shared__ int s[128];
    const int t = threadIdx.x;
    const int v = (t < NBLK) ? bsum[t] : 0;
    s[t] = v;
    __syncthreads();
    for (int off = 1; off < 128; off <<= 1) {
        int x = (t >= off) ? s[t - off] : 0;
        __syncthreads();
        s[t] += x;
        __syncthreads();
    }
    if (t < NBLK) bbase[t] = s[t] - v;
    if (t == 0) H0[NN] = NE;
}

// ---------------------------------------------------------------------------
// K4: per-chunk scan -> exact per-col offsets H0/cur, fused with
// dinv = rsqrt(deg+1) and row packing:
//   pack[r][0..20] = dinv[r]*{ux[r],mx[r]}, pack[r][21] = dinv[r] (96 B rows).
// All reads/writes coalesced at line level.
// ---------------------------------------------------------------------------
__global__ __launch_bounds__(1024) void offs_pack_kernel(const int* __restrict__ cnt,
                                                         const float* __restrict__ degf,
                                                         const int* __restrict__ bbase,
                                                         int* __restrict__ H0,
                                                         int* __restrict__ cur,
                                                         const float* __restrict__ ux,
                                                         const float* __restrict__ mx,
                                                         float* __restrict__ pack) {
    __shared__ int s[1024];
    const int t = threadIdx.x;
    const int g = blockIdx.x * 1024 + t;
    const int v = (g < NN) ? cnt[g] : 0;
    s[t] = v;
    __syncthreads();
    for (int off = 1; off < 1024; off <<= 1) {
        int x = (t >= off) ? s[t - off] : 0;
        __syncthreads();
        s[t] += x;
        __syncthreads();
    }
    if (g < NN) {
        const int base = bbase[blockIdx.x] + s[t] - v;
        H0[g] = base;
        cur[g] = base;
        const float d = rsqrtf(degf[g] + 1.0f);
        float* pr = pack + (size_t)g * 24;
        const float* u = ux + (size_t)g * 3;
        const float* m = mx + (size_t)g * 18;
        pr[0] = d * u[0];
        pr[1] = d * u[1];
        pr[2] = d * u[2];
#pragma unroll
        for (int k = 0; k < 18; k++) pr[3 + k] = d * m[k];
        pr[21] = d;
        pr[22] = 0.f;
        pr[23] = 0.f;
    }
}

// ---------------------------------------------------------------------------
// K5: scatter edges into col-contiguous runs via per-col cursors.
// mid[pos] = {row, ew_bits}. Exact layout, no CAP, no overflow.
// ---------------------------------------------------------------------------
__global__ __launch_bounds__(256) void scatter_kernel(const int* __restrict__ ei,
                                                      const float* __restrict__ ew,
                                                      int* __restrict__ cur,
                                                      int2* __restrict__ mid) {
    for (int e = blockIdx.x * 256 + threadIdx.x; e < NE; e += 1024 * 256) {
        const int c = ei[NE + e];
        const int r = ei[e];
        const float w = ew[e];
        const int pos = atomicAdd(&cur[c], 1);
        mid[pos] = make_int2(r, __float_as_int(w));
    }
}

// ---------------------------------------------------------------------------
// K6: aggregation + fused MLP. 4 lanes per column (sub = t&3), zero LDS,
// no sorting phases: edges already col-contiguous. Register accumulation,
// shfl_xor combine, MLP k-split 4 ways across the same lanes.
// ---------------------------------------------------------------------------
__global__ __launch_bounds__(256) void bagg_mlp_kernel(const int2* __restrict__ mid,
                                                       const int* __restrict__ H0,
                                                       const float* __restrict__ pack,
                                                       const float* __restrict__ Mt,
                                                       const float* __restrict__ b2,
                                                       float* __restrict__ out) {
    const int t = threadIdx.x;
    const int sub = t & 3;
    const int c = blockIdx.x * CPB + (t >> 2);

    float s21[21];
#pragma unroll
    for (int m = 0; m < 21; m++) s21[m] = 0.f;

    if (c < NN) {
        const int s0 = H0[c];
        const int s1 = H0[c + 1];
        for (int i = s0 + sub; i < s1; i += 4) {
            const int2 p = mid[i];
            const float w = __int_as_float(p.y);
            const float4* pr = (const float4*)(pack + (size_t)p.x * 24);
            const float4 v0 = pr[0];
            const float4 v1 = pr[1];
            const float4 v2 = pr[2];
            const float4 v3 = pr[3];
            const float4 v4 = pr[4];
            const float4 v5 = pr[5];
            s21[0]  = fmaf(w, v0.x, s21[0]);
            s21[1]  = fmaf(w, v0.y, s21[1]);
            s21[2]  = fmaf(w, v0.z, s21[2]);
            s21[3]  = fmaf(w, v0.w, s21[3]);
            s21[4]  = fmaf(w, v1.x, s21[4]);
            s21[5]  = fmaf(w, v1.y, s21[5]);
            s21[6]  = fmaf(w, v1.z, s21[6]);
            s21[7]  = fmaf(w, v1.w, s21[7]);
            s21[8]  = fmaf(w, v2.x, s21[8]);
            s21[9]  = fmaf(w, v2.y, s21[9]);
            s21[10] = fmaf(w, v2.z, s21[10]);
            s21[11] = fmaf(w, v2.w, s21[11]);
            s21[12] = fmaf(w, v3.x, s21[12]);
            s21[13] = fmaf(w, v3.y, s21[13]);
            s21[14] = fmaf(w, v3.z, s21[14]);
            s21[15] = fmaf(w, v3.w, s21[15]);
            s21[16] = fmaf(w, v4.x, s21[16]);
            s21[17] = fmaf(w, v4.y, s21[17]);
            s21[18] = fmaf(w, v4.z, s21[18]);
            s21[19] = fmaf(w, v4.w, s21[19]);
            s21[20] = fmaf(w, v5.x, s21[20]);
        }
    }

    // combine the 4 sub-lanes (butterfly within each aligned 4-lane group)
#pragma unroll
    for (int m = 0; m < 21; m++) {
        s21[m] += __shfl_xor(s21[m], 1);
        s21[m] += __shfl_xor(s21[m], 2);
    }

    float o = 0.f;
    if (c < NN) {
        // self-loop + dinv[c] scaling (all 4 lanes redundantly; cheap)
        const float4* pr = (const float4*)(pack + (size_t)c * 24);
        const float4 v0 = pr[0];
        const float4 v1 = pr[1];
        const float4 v2 = pr[2];
        const float4 v3 = pr[3];
        const float4 v4 = pr[4];
        const float4 v5 = pr[5];
        const float d = v5.y;
        s21[0]  = d * (s21[0]  + v0.x);
        s21[1]  = d * (s21[1]  + v0.y);
        s21[2]  = d * (s21[2]  + v0.z);
        s21[3]  = d * (s21[3]  + v0.w);
        s21[4]  = d * (s21[4]  + v1.x);
        s21[5]  = d * (s21[5]  + v1.y);
        s21[6]  = d * (s21[6]  + v1.z);
        s21[7]  = d * (s21[7]  + v1.w);
        s21[8]  = d * (s21[8]  + v2.x);
        s21[9]  = d * (s21[9]  + v2.y);
        s21[10] = d * (s21[10] + v2.z);
        s21[11] = d * (s21[11] + v2.w);
        s21[12] = d * (s21[12] + v3.x);
        s21[13] = d * (s21[13] + v3.y);
        s21[14] = d * (s21[14] + v3.z);
        s21[15] = d * (s21[15] + v3.w);
        s21[16] = d * (s21[16] + v4.x);
        s21[17] = d * (s21[17] + v4.y);
        s21[18] = d * (s21[18] + v4.z);
        s21[19] = d * (s21[19] + v4.w);
        s21[20] = d * (s21[20] + v5.x);

        // MLP: 32 hidden units per sub-lane (Mt rows L1-hot, 12 KB)
        const int k0 = sub * 32;
#pragma unroll 2
        for (int k = k0; k < k0 + 32; k++) {
            const float* r = Mt + k * 24;
            float h = r[21];
#pragma unroll
            for (int m = 0; m < 21; m++) h = fmaf(s21[m], r[m], h);
            o = fmaf(fmaxf(h, 0.f), r[22], o);
        }
    }
    o += __shfl_xor(o, 1);
    o += __shfl_xor(o, 2);
    if (sub == 0 && c < NN) out[c] = o + b2[0];
}

// ===========================================================================
extern "C" void kernel_launch(void* const* d_in, const int* in_sizes, int n_in,
                              void* d_out, int out_size, void* d_ws, size_t ws_size,
                              hipStream_t stream) {
    const float* ux = (const float*)d_in[0];   // user_x  [N,3]
    const float* mx = (const float*)d_in[1];   // movie_x [N,18]
    const int* ei = (const int*)d_in[2];       // edge_index [2,E] (int32)
    const float* ew = (const float*)d_in[3];   // edge_attr [E]
    const float* Wu = (const float*)d_in[4];   // [3,64]
    const float* bu = (const float*)d_in[5];   // [64]
    const float* Wm = (const float*)d_in[6];   // [18,64]
    const float* bm = (const float*)d_in[7];   // [64]
    const float* W1 = (const float*)d_in[8];   // [128,128]
    const float* b1 = (const float*)d_in[9];   // [128]
    const float* W2 = (const float*)d_in[10];  // [128,1]
    const float* b2 = (const float*)d_in[11];  // [1]
    float* out = (float*)d_out;

    char* ws = (char*)d_ws;
    int*   cnt   = (int*)ws;                     // @0          400,000 B
    float* degf  = (float*)(ws + 400000);        // @400,000    400,000 B
    int*   cur   = (int*)(ws + 800000);          // @800,000    400,000 B
    int*   H0    = (int*)(ws + 1200000);         // @1,200,000  400,004 B
    int*   bsum  = (int*)(ws + 1600016);         // @1,600,016  392 B
    int*   bbase = (int*)(ws + 1600416);         // @1,600,416  392 B
    float* Mt    = (float*)(ws + 1600816);       // @1,600,816  12,288 B (16B-aligned)
    float* pack  = (float*)(ws + 1613104);       // @1,613,104  9,600,000 B (16B-aligned)
    int2*  mid   = (int2*)(ws + 11213104);       // @11,213,104 8,000,000 B (8B-aligned)
    // total ~19.2 MB

    fuse_zero_kernel<<<257, 128, 0, stream>>>(Wu, bu, Wm, bm, W1, b1, W2, Mt, cnt);
    cnt_deg_kernel<<<1024, 256, 0, stream>>>(ei, ew, cnt, degf);
    bsum_kernel<<<NBLK, 1024, 0, stream>>>(cnt, bsum);
    bscan_kernel<<<1, 128, 0, stream>>>(bsum, bbase, H0);
    offs_pack_kernel<<<NBLK, 1024, 0, stream>>>(cnt, degf, bbase, H0, cur, ux, mx, pack);
    scatter_kernel<<<1024, 256, 0, stream>>>(ei, ew, cur, mid);
    bagg_mlp_kernel<<<(NN + CPB - 1) / CPB, 256, 0, stream>>>(mid, H0, pack, Mt, b2, out);
}

// Round 4
// 245.077 us; speedup vs baseline: 1.7741x; 1.7741x over previous
//
#include <hip/hip_runtime.h>
#include <hip/hip_fp16.h>

#define NN 100000
#define NE 1000000
#define BSH 7        // bucket shift: 128 cols per bucket
#define BCOLS 128
#define NBUCK 782    // ceil(NN / 128)
#define SBLK 256     // edge-partition blocks for count/scatter
#define SITER 16     // ceil(NE / (SBLK*256)) edges per scatter thread
#define CAP 2048     // max edges/bucket via LDS path (mean 1279, sd ~36)

// fp16 helpers -------------------------------------------------------------
__device__ __forceinline__ float2 h2f(unsigned u) {
    union { unsigned u; __half2 h; } c; c.u = u;
    return __half22float2(c.h);
}
__device__ __forceinline__ unsigned f2h2(float a, float b) {
    union { __half2 h; unsigned u; } c; c.h = __floats2half2_rn(a, b);
    return c.u;
}

// ---------------------------------------------------------------------------
// K_f: fuse the whole linear chain into Mt[128][24]:
//   Mt[k][0..20] = fused GCN->layer1 matrix column k ([Wu@W1_top; Wm@W1_bot])
//   Mt[k][21]    = b1'[k],  Mt[k][22] = W2[k]
// Also zeroes cnt[NBUCK].
// ---------------------------------------------------------------------------
__global__ __launch_bounds__(128) void fuse_kernel(const float* __restrict__ Wu,
                                                   const float* __restrict__ bu,
                                                   const float* __restrict__ Wm,
                                                   const float* __restrict__ bm,
                                                   const float* __restrict__ W1,
                                                   const float* __restrict__ b1,
                                                   const float* __restrict__ W2,
                                                   float* __restrict__ Mt,
                                                   int* __restrict__ cnt) {
    const int j = threadIdx.x;
    for (int i = j; i < NBUCK; i += 128) cnt[i] = 0;

    float w1c[128];
#pragma unroll
    for (int k = 0; k < 128; k++) w1c[k] = W1[k * 128 + j];

    float* row = Mt + j * 24;
#pragma unroll
    for (int m = 0; m < 3; m++) {
        float acc = 0.f;
#pragma unroll
        for (int k = 0; k < 64; k++) acc = fmaf(Wu[m * 64 + k], w1c[k], acc);
        row[m] = acc;
    }
#pragma unroll
    for (int m = 0; m < 18; m++) {
        float acc = 0.f;
#pragma unroll
        for (int k = 0; k < 64; k++) acc = fmaf(Wm[m * 64 + k], w1c[64 + k], acc);
        row[3 + m] = acc;
    }
    float bp = b1[j];
#pragma unroll
    for (int k = 0; k < 64; k++) {
        bp = fmaf(bu[k], w1c[k], bp);
        bp = fmaf(bm[k], w1c[64 + k], bp);
    }
    row[21] = bp;
    row[22] = W2[j];
    row[23] = 0.f;
}

// ---------------------------------------------------------------------------
// K_a: bucket counts. Per-block LDS histogram, then one global atomicAdd per
// (block,bucket) -- ~200K low-contention atomics.
// ---------------------------------------------------------------------------
__global__ __launch_bounds__(256) void bcnt_kernel(const int* __restrict__ col,
                                                   int* __restrict__ cnt) {
    __shared__ int h[NBUCK];
    for (int i = threadIdx.x; i < NBUCK; i += 256) h[i] = 0;
    __syncthreads();
    for (int e = blockIdx.x * 256 + threadIdx.x; e < NE; e += SBLK * 256)
        atomicAdd(&h[col[e] >> BSH], 1);
    __syncthreads();
    for (int i = threadIdx.x; i < NBUCK; i += 256)
        if (h[i]) atomicAdd(&cnt[i], h[i]);
}

// ---------------------------------------------------------------------------
// K_b: exclusive scan of 782 bucket counts (one block). Writes gbase
// (mutable reservation cursors) and H0 (immutable segment bounds).
// ---------------------------------------------------------------------------
__global__ __launch_bounds__(1024) void bscan_kernel(const int* __restrict__ cnt,
                                                     int* __restrict__ gbase,
                                                     int* __restrict__ H0) {
    __shared__ int s[1024];
    const int t = threadIdx.x;
    const int v = (t < NBUCK) ? cnt[t] : 0;
    s[t] = v;
    __syncthreads();
    for (int off = 1; off < 1024; off <<= 1) {
        int x = (t >= off) ? s[t - off] : 0;
        __syncthreads();
        s[t] += x;
        __syncthreads();
    }
    const int excl = s[t] - v;
    if (t < NBUCK) { gbase[t] = excl; H0[t] = excl; }
    if (t == 0) H0[NBUCK] = NE;
}

// ---------------------------------------------------------------------------
// K_c: scatter into bucket-contiguous runs. Single global read pass: edges
// staged in registers during the histogram, then scattered from registers.
// Payload: x = (col&127) | (row<<7) (17+7=24 bits), y = ew bits.
// ---------------------------------------------------------------------------
__global__ __launch_bounds__(256) void bscatter_kernel(const int* __restrict__ ei,
                                                       const float* __restrict__ ew,
                                                       int* __restrict__ gbase,
                                                       int2* __restrict__ mid) {
    __shared__ int h[NBUCK];
    __shared__ int rbase[NBUCK];
    int cs[SITER], rs[SITER];
    float wv[SITER];
    const int e0 = blockIdx.x * 256 + threadIdx.x;

    for (int i = threadIdx.x; i < NBUCK; i += 256) h[i] = 0;
    __syncthreads();
#pragma unroll
    for (int k = 0; k < SITER; k++) {
        const int e = e0 + k * (SBLK * 256);
        if (e < NE) {
            cs[k] = ei[NE + e];
            rs[k] = ei[e];
            wv[k] = ew[e];
            atomicAdd(&h[cs[k] >> BSH], 1);
        }
    }
    __syncthreads();
    for (int i = threadIdx.x; i < NBUCK; i += 256) {
        const int c0 = h[i];
        rbase[i] = c0 ? atomicAdd(&gbase[i], c0) : 0;
        h[i] = 0;   // reuse as running counter
    }
    __syncthreads();
#pragma unroll
    for (int k = 0; k < SITER; k++) {
        const int e = e0 + k * (SBLK * 256);
        if (e < NE) {
            const int bb = cs[k] >> BSH;
            const int pos = rbase[bb] + atomicAdd(&h[bb], 1);
            mid[pos] = make_int2((cs[k] & (BCOLS - 1)) | (rs[k] << BSH),
                                 __float_as_int(wv[k]));
        }
    }
}

// ---------------------------------------------------------------------------
// K_d: fused per-bucket degree + fp16 row packing.
//   dinv = rsqrt(deg+1)  (fp32 array, used exactly in the epilogue);
//   pack16[r][0..20] = fp16(dinv[r]*{ux[r],mx[r]}), [21] = fp16(dinv[r]),
//   rows padded to 32 halves = 64 B -> each edge gather touches ONE line.
// ---------------------------------------------------------------------------
__global__ __launch_bounds__(256) void bdeg_pack_kernel(const int2* __restrict__ mid,
                                                        const int* __restrict__ H0,
                                                        const float* __restrict__ ux,
                                                        const float* __restrict__ mx,
                                                        unsigned short* __restrict__ pack16,
                                                        float* __restrict__ dinv) {
    __shared__ float dl[BCOLS];
    const int b = blockIdx.x;
    const int t = threadIdx.x;
    if (t < BCOLS) dl[t] = 0.f;
    __syncthreads();
    const int start = H0[b];
    const int end = H0[b + 1];
    for (int i = start + t; i < end; i += 256) {
        const int2 p = mid[i];
        atomicAdd(&dl[p.x & (BCOLS - 1)], __int_as_float(p.y));
    }
    __syncthreads();
    if (t < BCOLS) {
        const int r = b * BCOLS + t;
        if (r < NN) {
            const float d = rsqrtf(dl[t] + 1.0f);
            dinv[r] = d;
            float v[22];
            const float* u = ux + (size_t)r * 3;
            const float* m = mx + (size_t)r * 18;
            v[0] = d * u[0];
            v[1] = d * u[1];
            v[2] = d * u[2];
#pragma unroll
            for (int k = 0; k < 18; k++) v[3 + k] = d * m[k];
            v[21] = d;
            unsigned wb[16];
#pragma unroll
            for (int k = 0; k < 11; k++) wb[k] = f2h2(v[2 * k], v[2 * k + 1]);
#pragma unroll
            for (int k = 11; k < 16; k++) wb[k] = 0u;
            uint4* dst = (uint4*)(pack16 + (size_t)r * 32);
            dst[0] = make_uint4(wb[0], wb[1], wb[2], wb[3]);
            dst[1] = make_uint4(wb[4], wb[5], wb[6], wb[7]);
            dst[2] = make_uint4(wb[8], wb[9], wb[10], wb[11]);
            dst[3] = make_uint4(wb[12], wb[13], wb[14], wb[15]);
        }
    }
}

// fp16 row accumulate: s21 += w * pack16row ----------------------------------
#define ACC_ROW(base)                                                        \
    {                                                                        \
        const uint4* pr_ = (const uint4*)(base);                             \
        const uint4 A_ = pr_[0];                                             \
        const uint4 B_ = pr_[1];                                             \
        const uint2 C_ = ((const uint2*)pr_)[4];                             \
        const unsigned D_ = ((const unsigned*)pr_)[10];                      \
        float2 f_;                                                           \
        f_ = h2f(A_.x); s21[0]  = fmaf(w, f_.x, s21[0]);  s21[1]  = fmaf(w, f_.y, s21[1]);  \
        f_ = h2f(A_.y); s21[2]  = fmaf(w, f_.x, s21[2]);  s21[3]  = fmaf(w, f_.y, s21[3]);  \
        f_ = h2f(A_.z); s21[4]  = fmaf(w, f_.x, s21[4]);  s21[5]  = fmaf(w, f_.y, s21[5]);  \
        f_ = h2f(A_.w); s21[6]  = fmaf(w, f_.x, s21[6]);  s21[7]  = fmaf(w, f_.y, s21[7]);  \
        f_ = h2f(B_.x); s21[8]  = fmaf(w, f_.x, s21[8]);  s21[9]  = fmaf(w, f_.y, s21[9]);  \
        f_ = h2f(B_.y); s21[10] = fmaf(w, f_.x, s21[10]); s21[11] = fmaf(w, f_.y, s21[11]); \
        f_ = h2f(B_.z); s21[12] = fmaf(w, f_.x, s21[12]); s21[13] = fmaf(w, f_.y, s21[13]); \
        f_ = h2f(B_.w); s21[14] = fmaf(w, f_.x, s21[14]); s21[15] = fmaf(w, f_.y, s21[15]); \
        f_ = h2f(C_.x); s21[16] = fmaf(w, f_.x, s21[16]); s21[17] = fmaf(w, f_.y, s21[17]); \
        f_ = h2f(C_.y); s21[18] = fmaf(w, f_.x, s21[18]); s21[19] = fmaf(w, f_.y, s21[19]); \
        f_ = h2f(D_);   s21[20] = fmaf(w, f_.x, s21[20]);                    \
    }

// ---------------------------------------------------------------------------
// K_e: per-bucket counting sort of PAYLOADS into LDS, then pair-lane register
// aggregation (col = t>>1, hf = t&1: owners wave-adjacent -> shfl combine,
// no LDS partial arrays) + fused MLP (k split 2-way). Wave-level scan.
// ---------------------------------------------------------------------------
__global__ __launch_bounds__(256) void bagg_mlp_kernel(const int2* __restrict__ mid,
                                                       const int* __restrict__ H0,
                                                       const unsigned short* __restrict__ pack16,
                                                       const float* __restrict__ dinv,
                                                       const float* __restrict__ Mt,
                                                       const float* __restrict__ b2,
                                                       float* __restrict__ out) {
    __shared__ int2 smid[CAP];          // 16 KB: sorted payloads
    __shared__ int ccnt[BCOLS];         // per-col counts
    __shared__ int cbase[BCOLS];        // inclusive scan
    __shared__ int cptr[BCOLS];         // running scatter pointers

    const int b = blockIdx.x;
    const int t = threadIdx.x;
    const int col = t >> 1;
    const int hf = t & 1;
    const int start = H0[b];
    const int end = H0[b + 1];
    const int seg = end - start;
    const int segc = seg < CAP ? seg : CAP;

    // phase 1: per-col counts (coalesced mid read #1)
    if (t < BCOLS) ccnt[t] = 0;
    __syncthreads();
    for (int i = t; i < segc; i += 256)
        atomicAdd(&ccnt[mid[start + i].x & (BCOLS - 1)], 1);
    __syncthreads();

    // phase 2: wave 0 scans the 128 counts (2 per lane, shfl_up)
    if (t < 64) {
        const int a = ccnt[2 * t];
        const int bb = ccnt[2 * t + 1];
        int p = a + bb;
#pragma unroll
        for (int d = 1; d < 64; d <<= 1) {
            const int x = __shfl_up(p, d, 64);
            if (t >= d) p += x;
        }
        cbase[2 * t] = p - bb;          // inclusive
        cbase[2 * t + 1] = p;
        cptr[2 * t] = p - bb - a;       // exclusive = scatter base
        cptr[2 * t + 1] = p - bb;
    }
    __syncthreads();

    // phase 3: scatter payloads into LDS sorted order (coalesced mid read #2)
    for (int i = t; i < segc; i += 256) {
        const int2 p = mid[start + i];
        const int pos = atomicAdd(&cptr[p.x & (BCOLS - 1)], 1);
        smid[pos] = p;
    }
    __syncthreads();

    // phase 4: register aggregation, 2 wave-adjacent lanes per col
    float s21[21];
#pragma unroll
    for (int m = 0; m < 21; m++) s21[m] = 0.f;

    const int s0 = (col == 0) ? 0 : cbase[col - 1];
    const int s1 = cbase[col];
    for (int i = s0 + hf; i < s1; i += 2) {
        const int2 p = smid[i];
        const unsigned row = ((unsigned)p.x) >> BSH;
        const float w = __int_as_float(p.y);
        ACC_ROW(pack16 + (size_t)row * 32);
    }
    // overflow edges beyond CAP (statistically never; correctness fallback)
    if (seg > CAP) {
        for (int i = CAP + hf; i < seg; i += 2) {
            const int2 p = mid[start + i];
            if ((p.x & (BCOLS - 1)) == col) {
                const unsigned row = ((unsigned)p.x) >> BSH;
                const float w = __int_as_float(p.y);
                ACC_ROW(pack16 + (size_t)row * 32);
            }
        }
    }

    // combine the lane pair (both lanes end with the full sum)
#pragma unroll
    for (int m = 0; m < 21; m++) s21[m] += __shfl_xor(s21[m], 1, 64);

    const int c = b * BCOLS + col;
    float o = 0.f;
    if (c < NN) {
        // self-loop + exact fp32 dinv[c] scaling
        const float d = dinv[c];
        {
            const float w = 1.0f;       // self-loop weight folded: p16 already dinv-scaled
            float* s21_alias = s21;     // ACC_ROW accumulates self row
            (void)s21_alias;
            ACC_ROW(pack16 + (size_t)c * 32);
        }
#pragma unroll
        for (int m = 0; m < 21; m++) s21[m] *= d;

        // fused MLP: 64 hidden units per lane of the pair
        const int k0 = hf * 64;
#pragma unroll 4
        for (int k = k0; k < k0 + 64; k++) {
            const float* r = Mt + k * 24;
            float hsum = r[21];
#pragma unroll
            for (int m = 0; m < 21; m++) hsum = fmaf(s21[m], r[m], hsum);
            o = fmaf(fmaxf(hsum, 0.f), r[22], o);
        }
    }
    o += __shfl_xor(o, 1, 64);
    if (!hf && c < NN) out[c] = o + b2[0];
}

// ===========================================================================
extern "C" void kernel_launch(void* const* d_in, const int* in_sizes, int n_in,
                              void* d_out, int out_size, void* d_ws, size_t ws_size,
                              hipStream_t stream) {
    const float* ux = (const float*)d_in[0];   // user_x  [N,3]
    const float* mx = (const float*)d_in[1];   // movie_x [N,18]
    const int* ei = (const int*)d_in[2];       // edge_index [2,E]
    const float* ew = (const float*)d_in[3];   // edge_attr [E]
    const float* Wu = (const float*)d_in[4];   // [3,64]
    const float* bu = (const float*)d_in[5];   // [64]
    const float* Wm = (const float*)d_in[6];   // [18,64]
    const float* bm = (const float*)d_in[7];   // [64]
    const float* W1 = (const float*)d_in[8];   // [128,128]
    const float* b1 = (const float*)d_in[9];   // [128]
    const float* W2 = (const float*)d_in[10];  // [128,1]
    const float* b2 = (const float*)d_in[11];  // [1]
    float* out = (float*)d_out;

    char* ws = (char*)d_ws;
    int*            cnt    = (int*)ws;                      // @0        3,128 B
    int*            gbase  = (int*)(ws + 4096);             // @4096     3,128 B
    int*            H0     = (int*)(ws + 8192);             // @8192     3,132 B
    float*          Mt     = (float*)(ws + 12288);          // @12288    12,288 B
    float*          dinv   = (float*)(ws + 24576);          // @24576    400,000 B
    unsigned short* pack16 = (unsigned short*)(ws + 424576);// @424576   6,400,000 B (64B-aligned)
    int2*           mid    = (int2*)(ws + 6824576);         // @6824576  8,000,000 B
    // total ~14.8 MB

    fuse_kernel<<<1, 128, 0, stream>>>(Wu, bu, Wm, bm, W1, b1, W2, Mt, cnt);
    bcnt_kernel<<<SBLK, 256, 0, stream>>>(ei + NE, cnt);
    bscan_kernel<<<1, 1024, 0, stream>>>(cnt, gbase, H0);
    bscatter_kernel<<<SBLK, 256, 0, stream>>>(ei, ew, gbase, mid);
    bdeg_pack_kernel<<<NBUCK, 256, 0, stream>>>(mid, H0, ux, mx, pack16, dinv);
    bagg_mlp_kernel<<<NBUCK, 256, 0, stream>>>(mid, H0, pack16, dinv, Mt, b2, out);
}

// Round 5
// 196.839 us; speedup vs baseline: 2.2088x; 1.2451x over previous
//
#include <hip/hip_runtime.h>
#include <hip/hip_fp16.h>

#define NN 100000
#define NE 1000000
#define BSH 7        // bucket shift: 128 cols per bucket
#define BCOLS 128
#define NBUCK 782    // ceil(NN / 128)
#define SBLK 256     // edge-partition blocks for count/scatter
#define SITER 16     // ceil(NE / (SBLK*256)) edges per scatter thread
#define CAP 2048     // max edges/bucket via LDS path (mean 1279, sd ~36)

// fp16 helpers -------------------------------------------------------------
__device__ __forceinline__ float2 h2f(unsigned u) {
    union { unsigned u; __half2 h; } c; c.u = u;
    return __half22float2(c.h);
}
__device__ __forceinline__ unsigned f2h2(float a, float b) {
    union { __half2 h; unsigned u; } c; c.h = __floats2half2_rn(a, b);
    return c.u;
}

// fp16 row accumulate: s21 += w * pack16row (rows 0..21 of 24-half row) ------
// 3 independent 16B loads; 11 cvt pairs; compiler pipelines across unroll-2.
#define ACC_ROW16(base)                                                      \
    {                                                                        \
        const uint4* pr_ = (const uint4*)(base);                             \
        const uint4 A_ = pr_[0];                                             \
        const uint4 B_ = pr_[1];                                             \
        const uint4 C_ = pr_[2];                                             \
        float2 f_;                                                           \
        f_ = h2f(A_.x); s21[0]  = fmaf(w, f_.x, s21[0]);  s21[1]  = fmaf(w, f_.y, s21[1]);  \
        f_ = h2f(A_.y); s21[2]  = fmaf(w, f_.x, s21[2]);  s21[3]  = fmaf(w, f_.y, s21[3]);  \
        f_ = h2f(A_.z); s21[4]  = fmaf(w, f_.x, s21[4]);  s21[5]  = fmaf(w, f_.y, s21[5]);  \
        f_ = h2f(A_.w); s21[6]  = fmaf(w, f_.x, s21[6]);  s21[7]  = fmaf(w, f_.y, s21[7]);  \
        f_ = h2f(B_.x); s21[8]  = fmaf(w, f_.x, s21[8]);  s21[9]  = fmaf(w, f_.y, s21[9]);  \
        f_ = h2f(B_.y); s21[10] = fmaf(w, f_.x, s21[10]); s21[11] = fmaf(w, f_.y, s21[11]); \
        f_ = h2f(B_.z); s21[12] = fmaf(w, f_.x, s21[12]); s21[13] = fmaf(w, f_.y, s21[13]); \
        f_ = h2f(B_.w); s21[14] = fmaf(w, f_.x, s21[14]); s21[15] = fmaf(w, f_.y, s21[15]); \
        f_ = h2f(C_.x); s21[16] = fmaf(w, f_.x, s21[16]); s21[17] = fmaf(w, f_.y, s21[17]); \
        f_ = h2f(C_.y); s21[18] = fmaf(w, f_.x, s21[18]); s21[19] = fmaf(w, f_.y, s21[19]); \
        f_ = h2f(C_.z); s21[20] = fmaf(w, f_.x, s21[20]);                    \
    }

// ---------------------------------------------------------------------------
// K_f: fuse the whole linear chain into Mt[128][24]; zeroes cnt[NBUCK].
// ---------------------------------------------------------------------------
__global__ __launch_bounds__(128) void fuse_kernel(const float* __restrict__ Wu,
                                                   const float* __restrict__ bu,
                                                   const float* __restrict__ Wm,
                                                   const float* __restrict__ bm,
                                                   const float* __restrict__ W1,
                                                   const float* __restrict__ b1,
                                                   const float* __restrict__ W2,
                                                   float* __restrict__ Mt,
                                                   int* __restrict__ cnt) {
    const int j = threadIdx.x;
    for (int i = j; i < NBUCK; i += 128) cnt[i] = 0;

    float w1c[128];
#pragma unroll
    for (int k = 0; k < 128; k++) w1c[k] = W1[k * 128 + j];

    float* row = Mt + j * 24;
#pragma unroll
    for (int m = 0; m < 3; m++) {
        float acc = 0.f;
#pragma unroll
        for (int k = 0; k < 64; k++) acc = fmaf(Wu[m * 64 + k], w1c[k], acc);
        row[m] = acc;
    }
#pragma unroll
    for (int m = 0; m < 18; m++) {
        float acc = 0.f;
#pragma unroll
        for (int k = 0; k < 64; k++) acc = fmaf(Wm[m * 64 + k], w1c[64 + k], acc);
        row[3 + m] = acc;
    }
    float bp = b1[j];
#pragma unroll
    for (int k = 0; k < 64; k++) {
        bp = fmaf(bu[k], w1c[k], bp);
        bp = fmaf(bm[k], w1c[64 + k], bp);
    }
    row[21] = bp;
    row[22] = W2[j];
    row[23] = 0.f;
}

// ---------------------------------------------------------------------------
// K_a: bucket counts (per-block LDS histogram + one global add per bucket).
// ---------------------------------------------------------------------------
__global__ __launch_bounds__(256) void bcnt_kernel(const int* __restrict__ col,
                                                   int* __restrict__ cnt) {
    __shared__ int h[NBUCK];
    for (int i = threadIdx.x; i < NBUCK; i += 256) h[i] = 0;
    __syncthreads();
    for (int e = blockIdx.x * 256 + threadIdx.x; e < NE; e += SBLK * 256)
        atomicAdd(&h[col[e] >> BSH], 1);
    __syncthreads();
    for (int i = threadIdx.x; i < NBUCK; i += 256)
        if (h[i]) atomicAdd(&cnt[i], h[i]);
}

// ---------------------------------------------------------------------------
// K_b: exclusive scan of 782 bucket counts.
// ---------------------------------------------------------------------------
__global__ __launch_bounds__(1024) void bscan_kernel(const int* __restrict__ cnt,
                                                     int* __restrict__ gbase,
                                                     int* __restrict__ H0) {
    __shared__ int s[1024];
    const int t = threadIdx.x;
    const int v = (t < NBUCK) ? cnt[t] : 0;
    s[t] = v;
    __syncthreads();
    for (int off = 1; off < 1024; off <<= 1) {
        int x = (t >= off) ? s[t - off] : 0;
        __syncthreads();
        s[t] += x;
        __syncthreads();
    }
    const int excl = s[t] - v;
    if (t < NBUCK) { gbase[t] = excl; H0[t] = excl; }
    if (t == 0) H0[NBUCK] = NE;
}

// ---------------------------------------------------------------------------
// K_c: scatter into bucket-contiguous runs; single global read pass.
// Payload: x = (col&127) | (row<<7), y = ew bits.
// ---------------------------------------------------------------------------
__global__ __launch_bounds__(256) void bscatter_kernel(const int* __restrict__ ei,
                                                       const float* __restrict__ ew,
                                                       int* __restrict__ gbase,
                                                       int2* __restrict__ mid) {
    __shared__ int h[NBUCK];
    __shared__ int rbase[NBUCK];
    int cs[SITER], rs[SITER];
    float wv[SITER];
    const int e0 = blockIdx.x * 256 + threadIdx.x;

    for (int i = threadIdx.x; i < NBUCK; i += 256) h[i] = 0;
    __syncthreads();
#pragma unroll
    for (int k = 0; k < SITER; k++) {
        const int e = e0 + k * (SBLK * 256);
        if (e < NE) {
            cs[k] = ei[NE + e];
            rs[k] = ei[e];
            wv[k] = ew[e];
            atomicAdd(&h[cs[k] >> BSH], 1);
        }
    }
    __syncthreads();
    for (int i = threadIdx.x; i < NBUCK; i += 256) {
        const int c0 = h[i];
        rbase[i] = c0 ? atomicAdd(&gbase[i], c0) : 0;
        h[i] = 0;
    }
    __syncthreads();
#pragma unroll
    for (int k = 0; k < SITER; k++) {
        const int e = e0 + k * (SBLK * 256);
        if (e < NE) {
            const int bb = cs[k] >> BSH;
            const int pos = rbase[bb] + atomicAdd(&h[bb], 1);
            mid[pos] = make_int2((cs[k] & (BCOLS - 1)) | (rs[k] << BSH),
                                 __float_as_int(wv[k]));
        }
    }
}

// ---------------------------------------------------------------------------
// K_d: fused per-bucket degree + fp16 row packing (rows 32 halves = 64 B).
// dinv kept fp32 for the exact epilogue scale.
// ---------------------------------------------------------------------------
__global__ __launch_bounds__(256) void bdeg_pack_kernel(const int2* __restrict__ mid,
                                                        const int* __restrict__ H0,
                                                        const float* __restrict__ ux,
                                                        const float* __restrict__ mx,
                                                        unsigned short* __restrict__ pack16,
                                                        float* __restrict__ dinv) {
    __shared__ float dl[BCOLS];
    const int b = blockIdx.x;
    const int t = threadIdx.x;
    if (t < BCOLS) dl[t] = 0.f;
    __syncthreads();
    const int start = H0[b];
    const int end = H0[b + 1];
    for (int i = start + t; i < end; i += 256) {
        const int2 p = mid[i];
        atomicAdd(&dl[p.x & (BCOLS - 1)], __int_as_float(p.y));
    }
    __syncthreads();
    if (t < BCOLS) {
        const int r = b * BCOLS + t;
        if (r < NN) {
            const float d = rsqrtf(dl[t] + 1.0f);
            dinv[r] = d;
            float v[22];
            const float* u = ux + (size_t)r * 3;
            const float* m = mx + (size_t)r * 18;
            v[0] = d * u[0];
            v[1] = d * u[1];
            v[2] = d * u[2];
#pragma unroll
            for (int k = 0; k < 18; k++) v[3 + k] = d * m[k];
            v[21] = d;
            unsigned wb[16];
#pragma unroll
            for (int k = 0; k < 11; k++) wb[k] = f2h2(v[2 * k], v[2 * k + 1]);
#pragma unroll
            for (int k = 11; k < 16; k++) wb[k] = 0u;
            uint4* dst = (uint4*)(pack16 + (size_t)r * 32);
            dst[0] = make_uint4(wb[0], wb[1], wb[2], wb[3]);
            dst[1] = make_uint4(wb[4], wb[5], wb[6], wb[7]);
            dst[2] = make_uint4(wb[8], wb[9], wb[10], wb[11]);
            dst[3] = make_uint4(wb[12], wb[13], wb[14], wb[15]);
        }
    }
}

// ---------------------------------------------------------------------------
// K_e: round-2 structure exactly (proven 67.5 us): per-bucket counting sort
// of payloads into LDS, 2-threads-per-col register aggregation (col=t&127,
// hf=t>>7, LDS sp[] combine), unroll-2 gather loop, MLP k-split 2-way.
// ONLY change vs round 2: gather operand is fp16 48B (3 loads) not fp32 96B.
// ---------------------------------------------------------------------------
__global__ __launch_bounds__(256) void bagg_mlp_kernel(const int2* __restrict__ mid,
                                                       const int* __restrict__ H0,
                                                       const unsigned short* __restrict__ pack16,
                                                       const float* __restrict__ dinv,
                                                       const float* __restrict__ Mt,
                                                       const float* __restrict__ b2,
                                                       float* __restrict__ out) {
    __shared__ int2 smid[CAP];          // 16 KB: sorted payloads
    __shared__ int ccnt[BCOLS];         // per-col counts
    __shared__ int cbase[BCOLS];        // inclusive scan
    __shared__ int cptr[BCOLS];         // running scatter pointers
    __shared__ float sp[BCOLS][21];     // pair partials / combined s21
    __shared__ float po[BCOLS];         // MLP half-1 partials

    const int b = blockIdx.x;
    const int t = threadIdx.x;
    const int col = t & (BCOLS - 1);
    const int hf = t >> 7;              // 0 or 1 (wave-uniform)
    const int start = H0[b];
    const int end = H0[b + 1];
    const int seg = end - start;
    const int segc = seg < CAP ? seg : CAP;

    // phase 1: per-col counts (coalesced mid read #1)
    if (t < BCOLS) ccnt[t] = 0;
    __syncthreads();
    for (int i = t; i < segc; i += 256)
        atomicAdd(&ccnt[mid[start + i].x & (BCOLS - 1)], 1);
    __syncthreads();

    // phase 2: wave 0 scans the 128 counts (2 per lane, shfl_up)
    if (t < 64) {
        const int a = ccnt[2 * t];
        const int bb = ccnt[2 * t + 1];
        int p = a + bb;
#pragma unroll
        for (int d = 1; d < 64; d <<= 1) {
            const int x = __shfl_up(p, d, 64);
            if (t >= d) p += x;
        }
        cbase[2 * t] = p - bb;          // inclusive
        cbase[2 * t + 1] = p;
        cptr[2 * t] = p - bb - a;       // exclusive = scatter base
        cptr[2 * t + 1] = p - bb;
    }
    __syncthreads();

    // phase 3: scatter payloads into LDS sorted order (coalesced mid read #2)
    for (int i = t; i < segc; i += 256) {
        const int2 p = mid[start + i];
        const int pos = atomicAdd(&cptr[p.x & (BCOLS - 1)], 1);
        smid[pos] = p;
    }
    __syncthreads();

    // phase 4: register aggregation, 2 threads per col (hf picks odd/even)
    float s21[21];
#pragma unroll
    for (int m = 0; m < 21; m++) s21[m] = 0.f;

    const int s0 = (col == 0) ? 0 : cbase[col - 1];
    const int s1 = cbase[col];
#pragma unroll 2
    for (int i = s0 + hf; i < s1; i += 2) {
        const int2 p = smid[i];
        const unsigned row = ((unsigned)p.x) >> BSH;
        const float w = __int_as_float(p.y);
        ACC_ROW16(pack16 + (size_t)row * 32);
    }

    // combine halves: hf=1 publishes, hf=0 owns the column
    if (hf) {
#pragma unroll
        for (int m = 0; m < 21; m++) sp[col][m] = s21[m];
    }
    __syncthreads();

    const int c = b * BCOLS + col;
    if (!hf) {
#pragma unroll
        for (int m = 0; m < 21; m++) s21[m] += sp[col][m];
        // overflow edges beyond CAP (statistically never; correctness fallback)
        if (seg > CAP) {
            for (int i = CAP; i < seg; i++) {
                const int2 p = mid[start + i];
                if ((p.x & (BCOLS - 1)) == col) {
                    const unsigned row = ((unsigned)p.x) >> BSH;
                    const float w = __int_as_float(p.y);
                    ACC_ROW16(pack16 + (size_t)row * 32);
                }
            }
        }
        if (c < NN) {
            // self-loop (pack row already dinv-scaled) + exact fp32 dinv[c]
            const float w = 1.0f;
            ACC_ROW16(pack16 + (size_t)c * 32);
            const float d = dinv[c];
#pragma unroll
            for (int m = 0; m < 21; m++) s21[m] *= d;
        }
#pragma unroll
        for (int m = 0; m < 21; m++) sp[col][m] = s21[m];
    }
    __syncthreads();
    if (hf) {
#pragma unroll
        for (int m = 0; m < 21; m++) s21[m] = sp[col][m];
    }

    // fused MLP, k split across halves (hf wave-uniform)
    float o = 0.f;
    const int k0 = hf * 64;
#pragma unroll 4
    for (int k = k0; k < k0 + 64; k++) {
        const float* r = Mt + k * 24;
        float hsum = r[21];
#pragma unroll
        for (int m = 0; m < 21; m++) hsum = fmaf(s21[m], r[m], hsum);
        o = fmaf(fmaxf(hsum, 0.f), r[22], o);
    }
    if (hf) po[col] = o;
    __syncthreads();
    if (!hf && c < NN) out[c] = o + po[col] + b2[0];
}

// ===========================================================================
extern "C" void kernel_launch(void* const* d_in, const int* in_sizes, int n_in,
                              void* d_out, int out_size, void* d_ws, size_t ws_size,
                              hipStream_t stream) {
    const float* ux = (const float*)d_in[0];   // user_x  [N,3]
    const float* mx = (const float*)d_in[1];   // movie_x [N,18]
    const int* ei = (const int*)d_in[2];       // edge_index [2,E]
    const float* ew = (const float*)d_in[3];   // edge_attr [E]
    const float* Wu = (const float*)d_in[4];   // [3,64]
    const float* bu = (const float*)d_in[5];   // [64]
    const float* Wm = (const float*)d_in[6];   // [18,64]
    const float* bm = (const float*)d_in[7];   // [64]
    const float* W1 = (const float*)d_in[8];   // [128,128]
    const float* b1 = (const float*)d_in[9];   // [128]
    const float* W2 = (const float*)d_in[10];  // [128,1]
    const float* b2 = (const float*)d_in[11];  // [1]
    float* out = (float*)d_out;

    char* ws = (char*)d_ws;
    int*            cnt    = (int*)ws;                      // @0        3,128 B
    int*            gbase  = (int*)(ws + 4096);             // @4096     3,128 B
    int*            H0     = (int*)(ws + 8192);             // @8192     3,132 B
    float*          Mt     = (float*)(ws + 12288);          // @12288    12,288 B
    float*          dinv   = (float*)(ws + 24576);          // @24576    400,000 B
    unsigned short* pack16 = (unsigned short*)(ws + 424576);// @424576   6,400,000 B (64B-aligned)
    int2*           mid    = (int2*)(ws + 6824576);         // @6824576  8,000,000 B
    // total ~14.8 MB

    fuse_kernel<<<1, 128, 0, stream>>>(Wu, bu, Wm, bm, W1, b1, W2, Mt, cnt);
    bcnt_kernel<<<SBLK, 256, 0, stream>>>(ei + NE, cnt);
    bscan_kernel<<<1, 1024, 0, stream>>>(cnt, gbase, H0);
    bscatter_kernel<<<SBLK, 256, 0, stream>>>(ei, ew, gbase, mid);
    bdeg_pack_kernel<<<NBUCK, 256, 0, stream>>>(mid, H0, ux, mx, pack16, dinv);
    bagg_mlp_kernel<<<NBUCK, 256, 0, stream>>>(mid, H0, pack16, dinv, Mt, b2, out);
}